// Round 17
// baseline (1457.259 us; speedup 1.0000x reference)
//
#include <hip/hip_runtime.h>
#include <hip/hip_fp16.h>

#define N_NODES 50000
#define N_EDGES 400000
#define NCLS 4
#define HID 32
#define HI 36                        // HID + IN_DIM
#define ROWS_P (N_NODES * NCLS)      // 200000 per-plane (n,c) rows
#define PADCAP 672000                // padded list capacity (32-sigma safe)
#define SLICES 8                     // XCD count (write-locality slicing)
#define BUCKS_PER_SLICE (N_NODES / SLICES)   // 6250
#define NCHUNKS ((N_NODES + 255) / 256)      // 196 scan chunks
#define GRIDE ((N_EDGES + 255) / 256)        // 1563
#define REP_PLANE (16 * N_NODES)     // 8 parts x 2 sides x N ints per plane

// Per-plane CSR block layout (ints). edgeRec first (16B aligned).
#define OFF_EREC 0
#define OFF_OFFS 1600000             // 3*(N+1) ints: inOffRaw | pinOff | poutOff
#define OFF_CNT  1750003             // 2*N ints: inCnt | outCnt (totals, by k_cvt)
#define OFF_BSUM 1850003             // 3*NCHUNKS
#define OFF_BOFF 1850591             // 3*NCHUNKS
#define OFF_PRT  1851180             // PADCAP ints region = 2*PADCAP u16 (16B aligned)
#define CSR_STRIDE 2523180           // ints; *4 bytes, 16B-aligned stride

// tanh(x) = 1 - 2/(1+exp(2x)); self-healing at the limits, no clamp needed.
__device__ __forceinline__ float fast_tanh(float x) {
    float e = __builtin_amdgcn_exp2f(x * 2.885390081777927f);   // exp(2x)
    float r = __builtin_amdgcn_rcpf(1.0f + e);
    return fmaf(-2.0f, r, 1.0f);
}

#if __has_builtin(__builtin_amdgcn_fdot2)
typedef _Float16 h2v __attribute__((ext_vector_type(2)));
__device__ __forceinline__ float fdot2f(__half2 a, __half2 b, float c) {
    return __builtin_amdgcn_fdot2(__builtin_bit_cast(h2v, a),
                                  __builtin_bit_cast(h2v, b), c, false);
}
#else
__device__ __forceinline__ float fdot2f(__half2 a, __half2 b, float c) {
    float2 af = __half22float2(a), bf = __half22float2(b);
    return c + af.x * bf.x + af.y * bf.y;
}
#endif

union F4H8 { float4 f4; __half2 h2[4]; };
union F2H4 { float2 f2; __half2 h2[2]; };

// Per plane: m[n][c][0:32] = tanh(x @ inW + inb), m[n][c][32:36] = x. m is fp16.
__global__ void k_init(const float* __restrict__ x, const float* __restrict__ W,
                       const float* __restrict__ b, __half* __restrict__ m) {
    unsigned t = blockIdx.x * 256 + threadIdx.x;
    if (t >= N_NODES * HI) return;
    unsigned idx = t % HI;
    unsigned n   = t / HI;
    float x0 = x[n * 4 + 0], x1 = x[n * 4 + 1];
    float x2 = x[n * 4 + 2], x3 = x[n * 4 + 3];
    float val;
    if (idx < 32) {
        float a = b[idx];
        a += x0 * W[idx] + x1 * W[32 + idx] + x2 * W[64 + idx] + x3 * W[96 + idx];
        val = fast_tanh(a);
    } else {
        val = (idx == 32) ? x0 : (idx == 33) ? x1 : (idx == 34) ? x2 : x3;
    }
    __half hv = __float2half_rn(val);
    __half* dst = m + (size_t)n * (NCLS * HI) + idx;
    dst[0] = hv; dst[HI] = hv; dst[2 * HI] = hv; dst[3 * HI] = hv;
}

// ---------------- CSR build ----------------
// Pass 1 (R17): per-PART replicated counters. part = chunk&7 -> under the
// round-robin blockIdx->XCD mapping each replica is touched by ONE XCD (no
// line ping-pong, R15's 97us pathology), while tmpLi stays dense-written
// (R16's sparse-write amplification avoided). rep[jj][part][side][n].
__global__ void k_pass1(const int* __restrict__ ei, int* __restrict__ rep,
                        int* __restrict__ tmpLi) {
    unsigned jj = blockIdx.x / GRIDE;
    unsigned chunk = blockIdx.x % GRIDE;
    unsigned part = chunk & 7;
    unsigned e = chunk * 256 + threadIdx.x;
    if (e >= N_EDGES) return;
    const int* rowI = ei + (size_t)jj * 2 * N_EDGES;
    const int* colI = rowI + N_EDGES;
    int* rp = rep + (size_t)jj * REP_PLANE + part * 2 * N_NODES;
    int r = rowI[e], cn = colI[e];
    int liIn  = atomicAdd(&rp[cn], 1);            // side 0: in (by col)
    int liOut = atomicAdd(&rp[N_NODES + r], 1);   // side 1: out (by row)
    tmpLi[(size_t)jj * N_EDGES + e] = liIn | (liOut << 16);
}

// Convert replicas -> per-(part,node) exclusive prefixes (in place) and
// per-node totals into OFF_CNT for the scan. grid: planes x 2 sides x NCHUNKS.
__global__ void k_cvt(int* __restrict__ rep, int* __restrict__ csr) {
    unsigned jj  = blockIdx.x / (2 * NCHUNKS);
    unsigned rem = blockIdx.x % (2 * NCHUNKS);
    unsigned s = rem / NCHUNKS, chunk = rem % NCHUNKS;
    unsigned n = chunk * 256 + threadIdx.x;
    if (n >= N_NODES) return;
    int* rp = rep + (size_t)jj * REP_PLANE + s * N_NODES + n;
    int running = 0;
#pragma unroll
    for (int p = 0; p < 8; ++p) {
        int t = rp[(size_t)p * 2 * N_NODES];
        rp[(size_t)p * 2 * N_NODES] = running;
        running += t;
    }
    (csr + (size_t)jj * CSR_STRIDE + OFF_CNT)[s * N_NODES + n] = running;
}

// Hierarchical scan, 3 variants/plane: v=0 raw-in; v=1 padded-8 in; v=2 padded-8 out.
__global__ void k_scanA(int* __restrict__ csr) {
    unsigned jj  = blockIdx.x / (3 * NCHUNKS);
    unsigned rem = blockIdx.x % (3 * NCHUNKS);
    unsigned v = rem / NCHUNKS, chunk = rem % NCHUNKS;
    int* base = csr + (size_t)jj * CSR_STRIDE;
    const int* cnt = base + OFF_CNT + (v == 2 ? N_NODES : 0);
    unsigned i = chunk * 256 + threadIdx.x;
    int val = (i < N_NODES) ? cnt[i] : 0;
    if (v) val = (val + 7) & ~7;
#pragma unroll
    for (int d = 1; d < 64; d <<= 1) val += __shfl_xor(val, d, 64);
    __shared__ int sh[4];
    unsigned lane = threadIdx.x & 63, wid = threadIdx.x >> 6;
    if (lane == 0) sh[wid] = val;
    __syncthreads();
    if (threadIdx.x == 0) (base + OFF_BSUM)[rem] = sh[0] + sh[1] + sh[2] + sh[3];
}

__global__ void k_scanB(int* __restrict__ csr) {
    unsigned jj = blockIdx.x / 3, v = blockIdx.x % 3;
    int* base = csr + (size_t)jj * CSR_STRIDE;
    const int* bsum = base + OFF_BSUM;
    int* boff = base + OFF_BOFF;
    int* offs = base + OFF_OFFS;
    int tid = threadIdx.x;           // 256
    int val = (tid < NCHUNKS) ? bsum[v * NCHUNKS + tid] : 0;
    int lane = tid & 63, wid = tid >> 6;
    int incl = val;
#pragma unroll
    for (int d = 1; d < 64; d <<= 1) {
        int t = __shfl_up(incl, d, 64);
        if (lane >= d) incl += t;
    }
    __shared__ int sh[4];
    if (lane == 63) sh[wid] = incl;
    __syncthreads();
    int waveOff = (wid == 0) ? 0 : (wid == 1) ? sh[0] :
                  (wid == 2) ? sh[0] + sh[1] : sh[0] + sh[1] + sh[2];
    incl += waveOff;
    if (tid < NCHUNKS) boff[v * NCHUNKS + tid] = incl - val;
    if (tid == NCHUNKS - 1) offs[(size_t)v * (N_NODES + 1) + N_NODES] = incl;
}

__global__ void k_scanC(int* __restrict__ csr) {
    unsigned jj  = blockIdx.x / (3 * NCHUNKS);
    unsigned rem = blockIdx.x % (3 * NCHUNKS);
    unsigned v = rem / NCHUNKS, chunk = rem % NCHUNKS;
    int* base = csr + (size_t)jj * CSR_STRIDE;
    const int* cnt = base + OFF_CNT + (v == 2 ? N_NODES : 0);
    const int* boff = base + OFF_BOFF;
    int* offs = base + OFF_OFFS;
    unsigned i = chunk * 256 + threadIdx.x;
    int val = (i < N_NODES) ? cnt[i] : 0;
    if (v) val = (val + 7) & ~7;
    int lane = threadIdx.x & 63, wid = threadIdx.x >> 6;
    int incl = val;
#pragma unroll
    for (int d = 1; d < 64; d <<= 1) {
        int t = __shfl_up(incl, d, 64);
        if (lane >= d) incl += t;
    }
    __shared__ int sh[4];
    if (lane == 63) sh[wid] = incl;
    __syncthreads();
    int waveOff = (wid == 0) ? 0 : (wid == 1) ? sh[0] :
                  (wid == 2) ? sh[0] + sh[1] : sh[0] + sh[1] + sh[2];
    if (i < N_NODES)
        offs[(size_t)v * (N_NODES + 1) + i] = boff[v * NCHUNKS + chunk] + incl + waveOff - val;
}

// Pass 2: XCD-sliced scatter. Rank within node = rep-prefix(part) + local li;
// part recomputed from e (part = (e>>8)&7, matching pass1's chunk&7).
// edgeRec = {row|col<<16, piP, poP, e}.
__global__ void k_pass2(const int* __restrict__ ei, int* __restrict__ csr,
                        const int* __restrict__ rep, const int* __restrict__ tmpLi) {
    unsigned jj  = blockIdx.x / (GRIDE * SLICES);
    unsigned rem = blockIdx.x % (GRIDE * SLICES);
    unsigned slice = rem & (SLICES - 1);
    unsigned e = (rem >> 3) * 256 + threadIdx.x;
    if (e >= N_EDGES) return;
    const int* rowI = ei + (size_t)jj * 2 * N_EDGES;
    const int* colI = rowI + N_EDGES;
    int* base = csr + (size_t)jj * CSR_STRIDE;
    const int* inOffRaw = base + OFF_OFFS;
    const int* pinOff   = inOffRaw + (N_NODES + 1);
    const int* poutOff  = pinOff + (N_NODES + 1);
    int4* edgeRec = (int4*)(base + OFF_EREC);
    unsigned short* inPrt  = (unsigned short*)(base + OFF_PRT);
    unsigned short* outPrt = inPrt + PADCAP;
    int r = rowI[e], cn = colI[e];
    unsigned part = (e >> 8) & 7;
    const int* rp = rep + (size_t)jj * REP_PLANE + part * 2 * N_NODES;
    int li = tmpLi[(size_t)jj * N_EDGES + e];
    unsigned lo = slice * BUCKS_PER_SLICE;
    if ((unsigned)(cn - lo) < BUCKS_PER_SLICE) {
        int rankIn = rp[cn] + (li & 0xFFFF);
        int rankOut = rp[N_NODES + r] + (int)(((unsigned)li) >> 16);
        int dense = inOffRaw[cn] + rankIn;
        int piP   = pinOff[cn] + rankIn;
        int poP   = poutOff[r] + rankOut;
        edgeRec[dense] = make_int4(r | (cn << 16), piP, poP, (int)e);
        inPrt[piP] = (unsigned short)r;
    }
    if ((unsigned)(r - lo) < BUCKS_PER_SLICE) {
        int rankOut = rp[N_NODES + r] + (int)(((unsigned)li) >> 16);
        int poP = poutOff[r] + rankOut;
        outPrt[poP] = (unsigned short)cn;
    }
}

// ---------------- per-iteration kernels ----------------

// Fused 5-plane GEMM, m fp16 + v_dot2_f32_f16.
__global__ void k_gemm5(const __half* __restrict__ m,
                        const float* __restrict__ eW1, const float* __restrict__ nW1,
                        const float* __restrict__ eb1, const float* __restrict__ nb1,
                        __half* __restrict__ u, __half* __restrict__ v,
                        __half* __restrict__ p, __half* __restrict__ q,
                        __half* __restrict__ r) {
    constexpr int RPB = 32;
    __shared__ __half sm[RPB * 40];       // 2.5 KB, 80B-stride rows
    unsigned tid = threadIdx.x;           // 320
    unsigned r0  = blockIdx.x * RPB;
    if (tid < RPB * 9) {                  // 288 x 8B = 32 rows x 72B
        uint2 d = reinterpret_cast<const uint2*>(m + (size_t)r0 * HI)[tid];
        unsigned row = tid / 9, off = tid % 9;
        *reinterpret_cast<uint2*>(sm + row * 40 + off * 4) = d;
    }
    unsigned o = tid % 160, grp = tid / 160;   // grp in {0,1}
    unsigned sub = o >> 5, oo = o & 31;
    const float* W = (sub == 0) ? eW1 : (sub == 1) ? eW1 + 36 * 32 :
                     (sub == 2) ? nW1 : (sub == 3) ? nW1 + 36 * 32 : nW1 + 72 * 32;
    __half* dsth   = (sub == 0) ? u : (sub == 1) ? v : (sub == 2) ? p :
                     (sub == 3) ? q : r;
    float bias = (sub == 0) ? eb1[oo] : (sub == 4) ? nb1[oo] : 0.f;
    __half2 wc[18];
#pragma unroll
    for (int t = 0; t < 18; ++t)
        wc[t] = __floats2half2_rn(W[(2 * t) * 32 + oo], W[(2 * t + 1) * 32 + oo]);
    __syncthreads();
#pragma unroll
    for (int i = 0; i < 16; ++i) {
        unsigned rloc = grp * 16 + i;
        const __half* rowp = sm + rloc * 40;
        F4H8 A0, A1, A2, A3; F2H4 A4;
        A0.f4 = *reinterpret_cast<const float4*>(rowp);
        A1.f4 = *reinterpret_cast<const float4*>(rowp + 8);
        A2.f4 = *reinterpret_cast<const float4*>(rowp + 16);
        A3.f4 = *reinterpret_cast<const float4*>(rowp + 24);
        A4.f2 = *reinterpret_cast<const float2*>(rowp + 32);
        float acc = bias;
#pragma unroll
        for (int t = 0; t < 4; ++t) acc = fdot2f(A0.h2[t], wc[t], acc);
#pragma unroll
        for (int t = 0; t < 4; ++t) acc = fdot2f(A1.h2[t], wc[4 + t], acc);
#pragma unroll
        for (int t = 0; t < 4; ++t) acc = fdot2f(A2.h2[t], wc[8 + t], acc);
#pragma unroll
        for (int t = 0; t < 4; ++t) acc = fdot2f(A3.h2[t], wc[12 + t], acc);
        acc = fdot2f(A4.h2[0], wc[16], acc);
        acc = fdot2f(A4.h2[1], wc[17], acc);
        dsth[(size_t)(r0 + rloc) * 32 + oo] = __float2half_rn(acc);
    }
}

// Final-pass projection: u|v only (256 threads). u gets +eb1.
__global__ void k_gemm2(const __half* __restrict__ m, const float* __restrict__ W0,
                        const float* __restrict__ W1, const float* __restrict__ eb1,
                        __half* __restrict__ o0, __half* __restrict__ o1) {
    constexpr int RPB = 32;
    __shared__ __half sm[RPB * 40];
    unsigned tid = threadIdx.x;           // 256
    unsigned r0  = blockIdx.x * RPB;
    for (unsigned i = tid; i < RPB * 9; i += 256) {
        uint2 d = reinterpret_cast<const uint2*>(m + (size_t)r0 * HI)[i];
        unsigned row = i / 9, off = i % 9;
        *reinterpret_cast<uint2*>(sm + row * 40 + off * 4) = d;
    }
    unsigned o = tid % 64, grp = tid / 64;     // 4 row-groups of 8
    unsigned sub = o >> 5, oo = o & 31;
    const float* W = sub ? W1 : W0;
    __half* dst    = sub ? o1 : o0;
    float bias = sub ? 0.f : eb1[oo];
    __half2 wc[18];
#pragma unroll
    for (int t = 0; t < 18; ++t)
        wc[t] = __floats2half2_rn(W[(2 * t) * 32 + oo], W[(2 * t + 1) * 32 + oo]);
    __syncthreads();
#pragma unroll
    for (int i = 0; i < 8; ++i) {
        unsigned rloc = grp * 8 + i;
        const __half* rowp = sm + rloc * 40;
        F4H8 A0, A1, A2, A3; F2H4 A4;
        A0.f4 = *reinterpret_cast<const float4*>(rowp);
        A1.f4 = *reinterpret_cast<const float4*>(rowp + 8);
        A2.f4 = *reinterpret_cast<const float4*>(rowp + 16);
        A3.f4 = *reinterpret_cast<const float4*>(rowp + 24);
        A4.f2 = *reinterpret_cast<const float2*>(rowp + 32);
        float acc = bias;
#pragma unroll
        for (int t = 0; t < 4; ++t) acc = fdot2f(A0.h2[t], wc[t], acc);
#pragma unroll
        for (int t = 0; t < 4; ++t) acc = fdot2f(A1.h2[t], wc[4 + t], acc);
#pragma unroll
        for (int t = 0; t < 4; ++t) acc = fdot2f(A2.h2[t], wc[8 + t], acc);
#pragma unroll
        for (int t = 0; t < 4; ++t) acc = fdot2f(A3.h2[t], wc[12 + t], acc);
        acc = fdot2f(A4.h2[0], wc[16], acc);
        acc = fdot2f(A4.h2[1], wc[17], acc);
        dst[(size_t)(r0 + rloc) * 32 + oo] = __float2half_rn(acc);
    }
}

// Edges in in-CSR order + XCD-chunked bijective swizzle (R13-proven).
// ea outputs TRANSPOSED: ea[c*PADCAP + slot].
template <bool FINAL>
__global__ void k_edge(const int4* __restrict__ edgeRec,
                       const __half* __restrict__ u, const __half* __restrict__ v,
                       const float* __restrict__ w2, const float* __restrict__ b2,
                       __half* __restrict__ eaIn, __half* __restrict__ eaOut,
                       float* __restrict__ dst) {
    unsigned nwg = gridDim.x, bid = blockIdx.x;
    unsigned qq = nwg >> 3, rr = nwg & 7;
    unsigned xcd = bid & 7, loc = bid >> 3;
    unsigned swz = (xcd < rr ? xcd * (qq + 1) : rr * (qq + 1) + (xcd - rr) * qq) + loc;
    unsigned g   = swz * 256 + threadIdx.x;          // exact grid: E*4
    unsigned c   = g & 3;
    unsigned idx = g >> 2;
    int4 rec = edgeRec[idx];
    unsigned rc  = (unsigned)rec.x;
    unsigned row = rc & 0xFFFFu, col = rc >> 16;
    const float4* u4 = reinterpret_cast<const float4*>(u + (col * 4 + c) * 32);
    const float4* v4 = reinterpret_cast<const float4*>(v + (row * 4 + c) * 32);
    float t2 = b2[0];
#pragma unroll
    for (int i = 0; i < 4; ++i) {          // 4 x (16B = 8 halves)
        F4H8 U, V; U.f4 = u4[i]; V.f4 = v4[i];
#pragma unroll
        for (int jj = 0; jj < 4; ++jj) {
            float2 sf = __half22float2(__hadd2(U.h2[jj], V.h2[jj]));
            int o = i * 8 + jj * 2;
            t2 += fast_tanh(sf.x) * w2[o];
            t2 += fast_tanh(sf.y) * w2[o + 1];
        }
    }
    float s  = fast_tanh(t2);
    float m1 = fmaxf(s, __shfl_xor(s, 1, 4));
    float mx = fmaxf(m1, __shfl_xor(m1, 2, 4));
    float ex = __expf(s - mx);
    float sm = ex + __shfl_xor(ex, 1, 4);
    sm = sm + __shfl_xor(sm, 2, 4);
    float val = ex * __builtin_amdgcn_rcpf(sm);
    if (FINAL) {
        dst[(unsigned)rec.w * 4 + c] = val;
    } else {
        __half hv = __float2half_rn(val);
        eaIn[(size_t)c * PADCAP + (unsigned)rec.y] = hv;
        eaOut[(size_t)c * PADCAP + (unsigned)rec.z] = hv;
    }
}

// Node net, ONE WAVE PER NODE (R10/R11-proven, 47.9us; four structural
// variants all lost to this): lane=(c2,k), 2x128B coalesced loads per edge,
// 16 loads per 8-edge batch; out-batch-0 metadata pre-issued; next-batch
// metadata prefetched; consume via v_pack + v_dot2_f32_f16.
__global__ void __launch_bounds__(64, 4)
k_node(__half* __restrict__ m, const __half* __restrict__ rbuf,
       const __half* __restrict__ p, const __half* __restrict__ q,
       const __half* __restrict__ eaInT, const __half* __restrict__ eaOutT,
       const int* __restrict__ pinOff, const int* __restrict__ poutOff,
       const unsigned short* __restrict__ inPrt,
       const unsigned short* __restrict__ outPrt,
       const float* __restrict__ nW2, const float* __restrict__ nb2) {
    unsigned lane = threadIdx.x;         // 64
    unsigned c2 = lane >> 5, k = lane & 31;
    unsigned n = blockIdx.x;
    unsigned gOff0 = c2 * 32 + k;
    unsigned gOff1 = gOff0 + 64;

    float h0 = __half2float(rbuf[((size_t)n * 4 + c2) * 32 + k]);      // class c2
    float h1 = __half2float(rbuf[((size_t)n * 4 + c2 + 2) * 32 + k]);  // class c2+2

    int bi0 = pinOff[n],  biE = pinOff[n + 1];
    int bo0 = poutOff[n], boE = poutOff[n + 1];
    __builtin_assume((bi0 & 7) == 0);
    __builtin_assume((bo0 & 7) == 0);

    const __half* eaI0 = eaInT + (size_t)c2 * PADCAP;
    const __half* eaI1 = eaInT + (size_t)(c2 + 2) * PADCAP;
    const __half* eaO0 = eaOutT + (size_t)c2 * PADCAP;
    const __half* eaO1 = eaOutT + (size_t)(c2 + 2) * PADCAP;

    auto accum = [&](const __half* __restrict__ base, uint4 prtv, uint4 e0v, uint4 e1v) {
        unsigned pr0 = prtv.x & 0xFFFFu, pr1 = prtv.x >> 16;
        unsigned pr2 = prtv.y & 0xFFFFu, pr3 = prtv.y >> 16;
        unsigned pr4 = prtv.z & 0xFFFFu, pr5 = prtv.z >> 16;
        unsigned pr6 = prtv.w & 0xFFFFu, pr7 = prtv.w >> 16;
        __half g0h[8], g1h[8];
        const __half* r0p = base + (size_t)pr0 * 128u; g0h[0] = r0p[gOff0]; g1h[0] = r0p[gOff1];
        const __half* r1p = base + (size_t)pr1 * 128u; g0h[1] = r1p[gOff0]; g1h[1] = r1p[gOff1];
        const __half* r2p = base + (size_t)pr2 * 128u; g0h[2] = r2p[gOff0]; g1h[2] = r2p[gOff1];
        const __half* r3p = base + (size_t)pr3 * 128u; g0h[3] = r3p[gOff0]; g1h[3] = r3p[gOff1];
        const __half* r4p = base + (size_t)pr4 * 128u; g0h[4] = r4p[gOff0]; g1h[4] = r4p[gOff1];
        const __half* r5p = base + (size_t)pr5 * 128u; g0h[5] = r5p[gOff0]; g1h[5] = r5p[gOff1];
        const __half* r6p = base + (size_t)pr6 * 128u; g0h[6] = r6p[gOff0]; g1h[6] = r6p[gOff1];
        const __half* r7p = base + (size_t)pr7 * 128u; g0h[7] = r7p[gOff0]; g1h[7] = r7p[gOff1];
        union { uint4 u4; __half2 h2[4]; } E0, E1;
        E0.u4 = e0v; E1.u4 = e1v;
#pragma unroll
        for (int ii = 0; ii < 4; ++ii) {   // v_pack + v_dot2_f32_f16
            h0 = fdot2f(E0.h2[ii], __halves2half2(g0h[2 * ii], g0h[2 * ii + 1]), h0);
            h1 = fdot2f(E1.h2[ii], __halves2half2(g1h[2 * ii], g1h[2 * ii + 1]), h1);
        }
    };

    // pre-issue first OUT batch metadata (hides its latency under the in-loop)
    uint4 oprt = {0, 0, 0, 0}, oe0 = {0, 0, 0, 0}, oe1 = {0, 0, 0, 0};
    if (bo0 < boE) {
        oprt = *(const uint4*)(outPrt + bo0);
        oe0  = *(const uint4*)(eaO0 + bo0);
        oe1  = *(const uint4*)(eaO1 + bo0);
    }

    if (bi0 < biE) {
        uint4 cprt = *(const uint4*)(inPrt + bi0);
        uint4 ce0  = *(const uint4*)(eaI0 + bi0);
        uint4 ce1  = *(const uint4*)(eaI1 + bi0);
        for (int b = bi0; b < biE; b += 8) {
            uint4 nprt = cprt, ne0 = ce0, ne1 = ce1;
            if (b + 8 < biE) {                       // prefetch next batch meta
                nprt = *(const uint4*)(inPrt + b + 8);
                ne0  = *(const uint4*)(eaI0 + b + 8);
                ne1  = *(const uint4*)(eaI1 + b + 8);
            }
            accum(p, cprt, ce0, ce1);
            cprt = nprt; ce0 = ne0; ce1 = ne1;
        }
    }
    if (bo0 < boE) {
        uint4 cprt = oprt, ce0 = oe0, ce1 = oe1;     // already in flight
        for (int b = bo0; b < boE; b += 8) {
            uint4 nprt = cprt, ne0 = ce0, ne1 = ce1;
            if (b + 8 < boE) {
                nprt = *(const uint4*)(outPrt + b + 8);
                ne0  = *(const uint4*)(eaO0 + b + 8);
                ne1  = *(const uint4*)(eaO1 + b + 8);
            }
            accum(q, cprt, ce0, ce1);
            cprt = nprt; ce0 = ne0; ce1 = ne1;
        }
    }

    float t0 = fast_tanh(h0);   // class c2, dim k (lane-local)
    float t1 = fast_tanh(h1);   // class c2+2, dim k
    float hh0 = nb2[k], hh1 = hh0;
#pragma unroll
    for (int kk = 0; kk < 32; ++kk) {
        float w = nW2[kk * 32 + k];                  // L1-resident broadcast
        float s0 = __shfl(t0, (int)(c2 * 32 + kk), 64);   // t(class c2, kk)
        float s1 = __shfl(t1, (int)(c2 * 32 + kk), 64);   // t(class c2+2, kk)
        hh0 += s0 * w;
        hh1 += s1 * w;
    }
    m[((size_t)n * 4 + c2) * HI + k]     = __float2half_rn(fast_tanh(hh0));
    m[((size_t)n * 4 + c2 + 2) * HI + k] = __float2half_rn(fast_tanh(hh1));
}

extern "C" void kernel_launch(void* const* d_in, const int* in_sizes, int n_in,
                              void* d_out, int out_size, void* d_ws, size_t ws_size,
                              hipStream_t stream) {
    const float* x   = (const float*)d_in[0];
    const int*   ei  = (const int*)d_in[1];
    const float* inW = (const float*)d_in[2];
    const float* inb = (const float*)d_in[3];
    const float* eW1 = (const float*)d_in[4];
    const float* eb1 = (const float*)d_in[5];
    const float* eW2 = (const float*)d_in[6];
    const float* eb2 = (const float*)d_in[7];
    const float* nW1 = (const float*)d_in[8];
    const float* nb1 = (const float*)d_in[9];
    const float* nW2 = (const float*)d_in[10];
    const float* nb2 = (const float*)d_in[11];
    float* out = (float*)d_out;

    // Workspace: m 14.4 | u..rbuf 64 | ea 10.75 | CSR blocks (10.09 MB each).
    // Merged mode needs 119.5 MB; falls back to per-plane rebuild otherwise.
    // rep (replicated counters, 9.6 MB merged / 3.2 MB per-plane) aliases v;
    // tmpLi (packed int, 4.8 MB) aliases u. Both dead until gemm5 runs.
    __half* m     = (__half*)d_ws;
    __half* u     = m + (size_t)ROWS_P * HI;
    __half* v     = u + (size_t)ROWS_P * 32;
    __half* p     = v + (size_t)ROWS_P * 32;
    __half* q     = p + (size_t)ROWS_P * 32;
    __half* rbuf  = q + (size_t)ROWS_P * 32;
    __half* eaIn  = rbuf + (size_t)ROWS_P * 32;
    __half* eaOut = eaIn + (size_t)PADCAP * 4;
    int*    csr   = (int*)(eaOut + (size_t)PADCAP * 4);   // 16B-aligned
    int*    tmpLi = (int*)u;                              // 4.8 MB <= u (12.8)
    int*    rep   = (int*)v;                              // 9.6 MB <= v (12.8)

    const size_t csrBaseBytes = (size_t)((char*)csr - (char*)d_ws);
    const bool merged = ws_size >= csrBaseBytes + 3u * (size_t)CSR_STRIDE * 4 + 256;

    const size_t zeroEA  = (size_t)PADCAP * 4 * 2 * 2;        // eaIn|eaOut
    const size_t prtB    = (size_t)2 * PADCAP * 2;

    if (merged) {   // build all 3 planes' CSR upfront (part-replicated atomics)
        hipMemsetAsync(rep, 0, (size_t)3 * REP_PLANE * 4, stream);
        for (int j = 0; j < 3; ++j)
            hipMemsetAsync(csr + (size_t)j * CSR_STRIDE + OFF_PRT, 0, prtB, stream);
        k_pass1<<<3 * GRIDE, 256, 0, stream>>>(ei, rep, tmpLi);
        k_cvt<<<3 * 2 * NCHUNKS, 256, 0, stream>>>(rep, csr);
        k_scanA<<<9 * NCHUNKS, 256, 0, stream>>>(csr);
        k_scanB<<<9, 256, 0, stream>>>(csr);
        k_scanC<<<9 * NCHUNKS, 256, 0, stream>>>(csr);
        k_pass2<<<3 * GRIDE * SLICES, 256, 0, stream>>>(ei, csr, rep, tmpLi);
    }

    for (int j = 0; j < 3; ++j) {
        const float* eW1j = eW1 + j * 72 * 32;
        const float* eb1j = eb1 + j * 32;
        const float* eW2j = eW2 + j * 32;
        const float* eb2j = eb2 + j;
        const float* nW1j = nW1 + j * 108 * 32;
        const float* nb1j = nb1 + j * 32;
        const float* nW2j = nW2 + j * 1024;
        const float* nb2j = nb2 + j * 32;

        int* bj = csr + (merged ? (size_t)j * CSR_STRIDE : 0);
        if (!merged) {   // per-plane rebuild into block 0 (same scheme, jj=0)
            hipMemsetAsync(rep, 0, (size_t)REP_PLANE * 4, stream);
            hipMemsetAsync(bj + OFF_PRT, 0, prtB, stream);
            k_pass1<<<GRIDE, 256, 0, stream>>>(ei + (size_t)j * 2 * N_EDGES, rep, tmpLi);
            k_cvt<<<2 * NCHUNKS, 256, 0, stream>>>(rep, bj);
            k_scanA<<<3 * NCHUNKS, 256, 0, stream>>>(bj);
            k_scanB<<<3, 256, 0, stream>>>(bj);
            k_scanC<<<3 * NCHUNKS, 256, 0, stream>>>(bj);
            k_pass2<<<GRIDE * SLICES, 256, 0, stream>>>(ei + (size_t)j * 2 * N_EDGES,
                                                        bj, rep, tmpLi);
        }
        const int4* edgeRec = (const int4*)(bj + OFF_EREC);
        const int*  pinOff  = bj + OFF_OFFS + (N_NODES + 1);
        const int*  poutOff = bj + OFF_OFFS + 2 * (N_NODES + 1);
        const unsigned short* inPrt  = (const unsigned short*)(bj + OFF_PRT);
        const unsigned short* outPrt = inPrt + PADCAP;

        hipMemsetAsync(eaIn, 0, zeroEA, stream);
        k_init<<<(N_NODES * HI + 255) / 256, 256, 0, stream>>>(
            x + (size_t)j * N_NODES * 4, inW + j * 128, inb + j * 32, m);

        for (int it = 0; it < 3; ++it) {
            k_gemm5<<<ROWS_P / 32, 320, 0, stream>>>(m, eW1j, nW1j, eb1j, nb1j,
                                                     u, v, p, q, rbuf);
            k_edge<false><<<N_EDGES * 4 / 256, 256, 0, stream>>>(
                edgeRec, u, v, eW2j, eb2j, eaIn, eaOut, nullptr);
            k_node<<<N_NODES, 64, 0, stream>>>(m, rbuf, p, q, eaIn, eaOut,
                                               pinOff, poutOff, inPrt, outPrt,
                                               nW2j, nb2j);
        }
        k_gemm2<<<ROWS_P / 32, 256, 0, stream>>>(m, eW1j, eW1j + 36 * 32, eb1j, u, v);
        k_edge<true><<<N_EDGES * 4 / 256, 256, 0, stream>>>(
            edgeRec, u, v, eW2j, eb2j, nullptr, nullptr,
            out + (size_t)j * N_EDGES * 4);
    }
}

// Round 18
// 1439.492 us; speedup vs baseline: 1.0123x; 1.0123x over previous
//
#include <hip/hip_runtime.h>
#include <hip/hip_fp16.h>

#define N_NODES 50000
#define N_EDGES 400000
#define NCLS 4
#define HID 32
#define HI 36                        // HID + IN_DIM
#define ROWS_P (N_NODES * NCLS)      // 200000 per-plane (n,c) rows
#define PADCAP 672000                // padded list capacity (32-sigma safe)
#define SLICES 8                     // XCD count (write-locality slicing)
#define BUCKS_PER_SLICE (N_NODES / SLICES)   // 6250
#define NCHUNKS ((N_NODES + 255) / 256)      // 196 scan chunks
#define GRIDE ((N_EDGES + 255) / 256)        // 1563

// Per-plane CSR block layout (ints). edgeRec first (16B aligned).
#define OFF_EREC 0
#define OFF_OFFS 1600000             // 3*(N+1) ints: inOffRaw | pinOff | poutOff
#define OFF_CNT  1750003             // 2*N ints: inCnt | outCnt
#define OFF_BSUM 1850003             // 3*NCHUNKS
#define OFF_BOFF 1850591             // 3*NCHUNKS
#define OFF_PRT  1851180             // PADCAP ints region = 2*PADCAP u16 (16B aligned)
#define CSR_STRIDE 2523180           // ints; *4 bytes, 16B-aligned stride

// tanh(x) = 1 - 2/(1+exp(2x)); self-healing at the limits, no clamp needed.
__device__ __forceinline__ float fast_tanh(float x) {
    float e = __builtin_amdgcn_exp2f(x * 2.885390081777927f);   // exp(2x)
    float r = __builtin_amdgcn_rcpf(1.0f + e);
    return fmaf(-2.0f, r, 1.0f);
}

#if __has_builtin(__builtin_amdgcn_fdot2)
typedef _Float16 h2v __attribute__((ext_vector_type(2)));
__device__ __forceinline__ float fdot2f(__half2 a, __half2 b, float c) {
    return __builtin_amdgcn_fdot2(__builtin_bit_cast(h2v, a),
                                  __builtin_bit_cast(h2v, b), c, false);
}
#else
__device__ __forceinline__ float fdot2f(__half2 a, __half2 b, float c) {
    float2 af = __half22float2(a), bf = __half22float2(b);
    return c + af.x * bf.x + af.y * bf.y;
}
#endif

union F4H8 { float4 f4; __half2 h2[4]; };
union F2H4 { float2 f2; __half2 h2[2]; };

// Per plane: m[n][c][0:32] = tanh(x @ inW + inb), m[n][c][32:36] = x. m is fp16.
__global__ void k_init(const float* __restrict__ x, const float* __restrict__ W,
                       const float* __restrict__ b, __half* __restrict__ m) {
    unsigned t = blockIdx.x * 256 + threadIdx.x;
    if (t >= N_NODES * HI) return;
    unsigned idx = t % HI;
    unsigned n   = t / HI;
    float x0 = x[n * 4 + 0], x1 = x[n * 4 + 1];
    float x2 = x[n * 4 + 2], x3 = x[n * 4 + 3];
    float val;
    if (idx < 32) {
        float a = b[idx];
        a += x0 * W[idx] + x1 * W[32 + idx] + x2 * W[64 + idx] + x3 * W[96 + idx];
        val = fast_tanh(a);
    } else {
        val = (idx == 32) ? x0 : (idx == 33) ? x1 : (idx == 34) ? x2 : x3;
    }
    __half hv = __float2half_rn(val);
    __half* dst = m + (size_t)n * (NCLS * HI) + idx;
    dst[0] = hv; dst[HI] = hv; dst[2 * HI] = hv; dst[3 * HI] = hv;
}

// ---------------- CSR build (plane-parameterized: jj from blockIdx) --------
// Pass 1: single atomic pass; local indices packed into tmpLi[jj*E + e].
// NOTE (R16/R17 lesson): the ~79MB WRITE_SIZE here tracks the atomic COUNT,
// not counter placement -- device-scope atomics execute at the cross-XCD
// coherence point, so locality schemes (dest-slicing, replication) don't
// reduce it. This simple form is the fastest of the three tried.
__global__ void k_pass1(const int* __restrict__ ei, int* __restrict__ csr,
                        int* __restrict__ tmpLi) {
    unsigned jj = blockIdx.x / GRIDE;
    unsigned e  = (blockIdx.x % GRIDE) * 256 + threadIdx.x;
    if (e >= N_EDGES) return;
    const int* rowI = ei + (size_t)jj * 2 * N_EDGES;
    const int* colI = rowI + N_EDGES;
    int* base   = csr + (size_t)jj * CSR_STRIDE;
    int* inCnt  = base + OFF_CNT;
    int* outCnt = inCnt + N_NODES;
    int r = rowI[e], cn = colI[e];
    int liIn  = atomicAdd(&inCnt[cn], 1);
    int liOut = atomicAdd(&outCnt[r], 1);
    tmpLi[(size_t)jj * N_EDGES + e] = liIn | (liOut << 16);
}

// Hierarchical scan, 3 variants/plane: v=0 raw-in; v=1 padded-8 in; v=2 padded-8 out.
__global__ void k_scanA(int* __restrict__ csr) {
    unsigned jj  = blockIdx.x / (3 * NCHUNKS);
    unsigned rem = blockIdx.x % (3 * NCHUNKS);
    unsigned v = rem / NCHUNKS, chunk = rem % NCHUNKS;
    int* base = csr + (size_t)jj * CSR_STRIDE;
    const int* cnt = base + OFF_CNT + (v == 2 ? N_NODES : 0);
    unsigned i = chunk * 256 + threadIdx.x;
    int val = (i < N_NODES) ? cnt[i] : 0;
    if (v) val = (val + 7) & ~7;
#pragma unroll
    for (int d = 1; d < 64; d <<= 1) val += __shfl_xor(val, d, 64);
    __shared__ int sh[4];
    unsigned lane = threadIdx.x & 63, wid = threadIdx.x >> 6;
    if (lane == 0) sh[wid] = val;
    __syncthreads();
    if (threadIdx.x == 0) (base + OFF_BSUM)[rem] = sh[0] + sh[1] + sh[2] + sh[3];
}

__global__ void k_scanB(int* __restrict__ csr) {
    unsigned jj = blockIdx.x / 3, v = blockIdx.x % 3;
    int* base = csr + (size_t)jj * CSR_STRIDE;
    const int* bsum = base + OFF_BSUM;
    int* boff = base + OFF_BOFF;
    int* offs = base + OFF_OFFS;
    int tid = threadIdx.x;           // 256
    int val = (tid < NCHUNKS) ? bsum[v * NCHUNKS + tid] : 0;
    int lane = tid & 63, wid = tid >> 6;
    int incl = val;
#pragma unroll
    for (int d = 1; d < 64; d <<= 1) {
        int t = __shfl_up(incl, d, 64);
        if (lane >= d) incl += t;
    }
    __shared__ int sh[4];
    if (lane == 63) sh[wid] = incl;
    __syncthreads();
    int waveOff = (wid == 0) ? 0 : (wid == 1) ? sh[0] :
                  (wid == 2) ? sh[0] + sh[1] : sh[0] + sh[1] + sh[2];
    incl += waveOff;
    if (tid < NCHUNKS) boff[v * NCHUNKS + tid] = incl - val;
    if (tid == NCHUNKS - 1) offs[(size_t)v * (N_NODES + 1) + N_NODES] = incl;
}

__global__ void k_scanC(int* __restrict__ csr) {
    unsigned jj  = blockIdx.x / (3 * NCHUNKS);
    unsigned rem = blockIdx.x % (3 * NCHUNKS);
    unsigned v = rem / NCHUNKS, chunk = rem % NCHUNKS;
    int* base = csr + (size_t)jj * CSR_STRIDE;
    const int* cnt = base + OFF_CNT + (v == 2 ? N_NODES : 0);
    const int* boff = base + OFF_BOFF;
    int* offs = base + OFF_OFFS;
    unsigned i = chunk * 256 + threadIdx.x;
    int val = (i < N_NODES) ? cnt[i] : 0;
    if (v) val = (val + 7) & ~7;
    int lane = threadIdx.x & 63, wid = threadIdx.x >> 6;
    int incl = val;
#pragma unroll
    for (int d = 1; d < 64; d <<= 1) {
        int t = __shfl_up(incl, d, 64);
        if (lane >= d) incl += t;
    }
    __shared__ int sh[4];
    if (lane == 63) sh[wid] = incl;
    __syncthreads();
    int waveOff = (wid == 0) ? 0 : (wid == 1) ? sh[0] :
                  (wid == 2) ? sh[0] + sh[1] : sh[0] + sh[1] + sh[2];
    if (i < N_NODES)
        offs[(size_t)v * (N_NODES + 1) + i] = boff[v * NCHUNKS + chunk] + incl + waveOff - val;
}

// Pass 2: XCD-sliced scatter. edgeRec = {row|col<<16, piP, poP, e}.
__global__ void k_pass2(const int* __restrict__ ei, int* __restrict__ csr,
                        const int* __restrict__ tmpLi) {
    unsigned jj  = blockIdx.x / (GRIDE * SLICES);
    unsigned rem = blockIdx.x % (GRIDE * SLICES);
    unsigned slice = rem & (SLICES - 1);
    unsigned e = (rem >> 3) * 256 + threadIdx.x;
    if (e >= N_EDGES) return;
    const int* rowI = ei + (size_t)jj * 2 * N_EDGES;
    const int* colI = rowI + N_EDGES;
    int* base = csr + (size_t)jj * CSR_STRIDE;
    const int* inOffRaw = base + OFF_OFFS;
    const int* pinOff   = inOffRaw + (N_NODES + 1);
    const int* poutOff  = pinOff + (N_NODES + 1);
    int4* edgeRec = (int4*)(base + OFF_EREC);
    unsigned short* inPrt  = (unsigned short*)(base + OFF_PRT);
    unsigned short* outPrt = inPrt + PADCAP;
    int r = rowI[e], cn = colI[e];
    int li = tmpLi[(size_t)jj * N_EDGES + e];
    int liIn  = li & 0xFFFF;
    int liOut = (int)(((unsigned)li) >> 16);
    unsigned lo = slice * BUCKS_PER_SLICE;
    if ((unsigned)(cn - lo) < BUCKS_PER_SLICE) {
        int dense = inOffRaw[cn] + liIn;
        int piP   = pinOff[cn] + liIn;
        int poP   = poutOff[r] + liOut;
        edgeRec[dense] = make_int4(r | (cn << 16), piP, poP, (int)e);
        inPrt[piP] = (unsigned short)r;
    }
    if ((unsigned)(r - lo) < BUCKS_PER_SLICE) {
        int poP = poutOff[r] + liOut;
        outPrt[poP] = (unsigned short)cn;
    }
}

// ---------------- per-iteration kernels ----------------

// Fused 5-plane GEMM, m fp16 + v_dot2_f32_f16.
__global__ void k_gemm5(const __half* __restrict__ m,
                        const float* __restrict__ eW1, const float* __restrict__ nW1,
                        const float* __restrict__ eb1, const float* __restrict__ nb1,
                        __half* __restrict__ u, __half* __restrict__ v,
                        __half* __restrict__ p, __half* __restrict__ q,
                        __half* __restrict__ r) {
    constexpr int RPB = 32;
    __shared__ __half sm[RPB * 40];       // 2.5 KB, 80B-stride rows
    unsigned tid = threadIdx.x;           // 320
    unsigned r0  = blockIdx.x * RPB;
    if (tid < RPB * 9) {                  // 288 x 8B = 32 rows x 72B
        uint2 d = reinterpret_cast<const uint2*>(m + (size_t)r0 * HI)[tid];
        unsigned row = tid / 9, off = tid % 9;
        *reinterpret_cast<uint2*>(sm + row * 40 + off * 4) = d;
    }
    unsigned o = tid % 160, grp = tid / 160;   // grp in {0,1}
    unsigned sub = o >> 5, oo = o & 31;
    const float* W = (sub == 0) ? eW1 : (sub == 1) ? eW1 + 36 * 32 :
                     (sub == 2) ? nW1 : (sub == 3) ? nW1 + 36 * 32 : nW1 + 72 * 32;
    __half* dsth   = (sub == 0) ? u : (sub == 1) ? v : (sub == 2) ? p :
                     (sub == 3) ? q : r;
    float bias = (sub == 0) ? eb1[oo] : (sub == 4) ? nb1[oo] : 0.f;
    __half2 wc[18];
#pragma unroll
    for (int t = 0; t < 18; ++t)
        wc[t] = __floats2half2_rn(W[(2 * t) * 32 + oo], W[(2 * t + 1) * 32 + oo]);
    __syncthreads();
#pragma unroll
    for (int i = 0; i < 16; ++i) {
        unsigned rloc = grp * 16 + i;
        const __half* rowp = sm + rloc * 40;
        F4H8 A0, A1, A2, A3; F2H4 A4;
        A0.f4 = *reinterpret_cast<const float4*>(rowp);
        A1.f4 = *reinterpret_cast<const float4*>(rowp + 8);
        A2.f4 = *reinterpret_cast<const float4*>(rowp + 16);
        A3.f4 = *reinterpret_cast<const float4*>(rowp + 24);
        A4.f2 = *reinterpret_cast<const float2*>(rowp + 32);
        float acc = bias;
#pragma unroll
        for (int t = 0; t < 4; ++t) acc = fdot2f(A0.h2[t], wc[t], acc);
#pragma unroll
        for (int t = 0; t < 4; ++t) acc = fdot2f(A1.h2[t], wc[4 + t], acc);
#pragma unroll
        for (int t = 0; t < 4; ++t) acc = fdot2f(A2.h2[t], wc[8 + t], acc);
#pragma unroll
        for (int t = 0; t < 4; ++t) acc = fdot2f(A3.h2[t], wc[12 + t], acc);
        acc = fdot2f(A4.h2[0], wc[16], acc);
        acc = fdot2f(A4.h2[1], wc[17], acc);
        dsth[(size_t)(r0 + rloc) * 32 + oo] = __float2half_rn(acc);
    }
}

// Final-pass projection: u|v only (256 threads). u gets +eb1.
__global__ void k_gemm2(const __half* __restrict__ m, const float* __restrict__ W0,
                        const float* __restrict__ W1, const float* __restrict__ eb1,
                        __half* __restrict__ o0, __half* __restrict__ o1) {
    constexpr int RPB = 32;
    __shared__ __half sm[RPB * 40];
    unsigned tid = threadIdx.x;           // 256
    unsigned r0  = blockIdx.x * RPB;
    for (unsigned i = tid; i < RPB * 9; i += 256) {
        uint2 d = reinterpret_cast<const uint2*>(m + (size_t)r0 * HI)[i];
        unsigned row = i / 9, off = i % 9;
        *reinterpret_cast<uint2*>(sm + row * 40 + off * 4) = d;
    }
    unsigned o = tid % 64, grp = tid / 64;     // 4 row-groups of 8
    unsigned sub = o >> 5, oo = o & 31;
    const float* W = sub ? W1 : W0;
    __half* dst    = sub ? o1 : o0;
    float bias = sub ? 0.f : eb1[oo];
    __half2 wc[18];
#pragma unroll
    for (int t = 0; t < 18; ++t)
        wc[t] = __floats2half2_rn(W[(2 * t) * 32 + oo], W[(2 * t + 1) * 32 + oo]);
    __syncthreads();
#pragma unroll
    for (int i = 0; i < 8; ++i) {
        unsigned rloc = grp * 8 + i;
        const __half* rowp = sm + rloc * 40;
        F4H8 A0, A1, A2, A3; F2H4 A4;
        A0.f4 = *reinterpret_cast<const float4*>(rowp);
        A1.f4 = *reinterpret_cast<const float4*>(rowp + 8);
        A2.f4 = *reinterpret_cast<const float4*>(rowp + 16);
        A3.f4 = *reinterpret_cast<const float4*>(rowp + 24);
        A4.f2 = *reinterpret_cast<const float2*>(rowp + 32);
        float acc = bias;
#pragma unroll
        for (int t = 0; t < 4; ++t) acc = fdot2f(A0.h2[t], wc[t], acc);
#pragma unroll
        for (int t = 0; t < 4; ++t) acc = fdot2f(A1.h2[t], wc[4 + t], acc);
#pragma unroll
        for (int t = 0; t < 4; ++t) acc = fdot2f(A2.h2[t], wc[8 + t], acc);
#pragma unroll
        for (int t = 0; t < 4; ++t) acc = fdot2f(A3.h2[t], wc[12 + t], acc);
        acc = fdot2f(A4.h2[0], wc[16], acc);
        acc = fdot2f(A4.h2[1], wc[17], acc);
        dst[(size_t)(r0 + rloc) * 32 + oo] = __float2half_rn(acc);
    }
}

// Edges in in-CSR order + XCD-chunked bijective swizzle (R13-proven).
// ea outputs TRANSPOSED: ea[c*PADCAP + slot].
template <bool FINAL>
__global__ void k_edge(const int4* __restrict__ edgeRec,
                       const __half* __restrict__ u, const __half* __restrict__ v,
                       const float* __restrict__ w2, const float* __restrict__ b2,
                       __half* __restrict__ eaIn, __half* __restrict__ eaOut,
                       float* __restrict__ dst) {
    unsigned nwg = gridDim.x, bid = blockIdx.x;
    unsigned qq = nwg >> 3, rr = nwg & 7;
    unsigned xcd = bid & 7, loc = bid >> 3;
    unsigned swz = (xcd < rr ? xcd * (qq + 1) : rr * (qq + 1) + (xcd - rr) * qq) + loc;
    unsigned g   = swz * 256 + threadIdx.x;          // exact grid: E*4
    unsigned c   = g & 3;
    unsigned idx = g >> 2;
    int4 rec = edgeRec[idx];
    unsigned rc  = (unsigned)rec.x;
    unsigned row = rc & 0xFFFFu, col = rc >> 16;
    const float4* u4 = reinterpret_cast<const float4*>(u + (col * 4 + c) * 32);
    const float4* v4 = reinterpret_cast<const float4*>(v + (row * 4 + c) * 32);
    float t2 = b2[0];
#pragma unroll
    for (int i = 0; i < 4; ++i) {          // 4 x (16B = 8 halves)
        F4H8 U, V; U.f4 = u4[i]; V.f4 = v4[i];
#pragma unroll
        for (int jj = 0; jj < 4; ++jj) {
            float2 sf = __half22float2(__hadd2(U.h2[jj], V.h2[jj]));
            int o = i * 8 + jj * 2;
            t2 += fast_tanh(sf.x) * w2[o];
            t2 += fast_tanh(sf.y) * w2[o + 1];
        }
    }
    float s  = fast_tanh(t2);
    float m1 = fmaxf(s, __shfl_xor(s, 1, 4));
    float mx = fmaxf(m1, __shfl_xor(m1, 2, 4));
    float ex = __expf(s - mx);
    float sm = ex + __shfl_xor(ex, 1, 4);
    sm = sm + __shfl_xor(sm, 2, 4);
    float val = ex * __builtin_amdgcn_rcpf(sm);
    if (FINAL) {
        dst[(unsigned)rec.w * 4 + c] = val;
    } else {
        __half hv = __float2half_rn(val);
        eaIn[(size_t)c * PADCAP + (unsigned)rec.y] = hv;
        eaOut[(size_t)c * PADCAP + (unsigned)rec.z] = hv;
    }
}

// Node net, ONE WAVE PER NODE (R10/R11-proven, 47.9us; four structural
// variants -- dword remap, node pairing, same-node split, persistent --
// all lost to this): lane=(c2,k), 2x128B coalesced loads per edge, 16 loads
// per 8-edge batch; out-batch-0 metadata pre-issued; next-batch metadata
// prefetched; consume via v_pack + v_dot2_f32_f16.
__global__ void __launch_bounds__(64, 4)
k_node(__half* __restrict__ m, const __half* __restrict__ rbuf,
       const __half* __restrict__ p, const __half* __restrict__ q,
       const __half* __restrict__ eaInT, const __half* __restrict__ eaOutT,
       const int* __restrict__ pinOff, const int* __restrict__ poutOff,
       const unsigned short* __restrict__ inPrt,
       const unsigned short* __restrict__ outPrt,
       const float* __restrict__ nW2, const float* __restrict__ nb2) {
    unsigned lane = threadIdx.x;         // 64
    unsigned c2 = lane >> 5, k = lane & 31;
    unsigned n = blockIdx.x;
    unsigned gOff0 = c2 * 32 + k;
    unsigned gOff1 = gOff0 + 64;

    float h0 = __half2float(rbuf[((size_t)n * 4 + c2) * 32 + k]);      // class c2
    float h1 = __half2float(rbuf[((size_t)n * 4 + c2 + 2) * 32 + k]);  // class c2+2

    int bi0 = pinOff[n],  biE = pinOff[n + 1];
    int bo0 = poutOff[n], boE = poutOff[n + 1];
    __builtin_assume((bi0 & 7) == 0);
    __builtin_assume((bo0 & 7) == 0);

    const __half* eaI0 = eaInT + (size_t)c2 * PADCAP;
    const __half* eaI1 = eaInT + (size_t)(c2 + 2) * PADCAP;
    const __half* eaO0 = eaOutT + (size_t)c2 * PADCAP;
    const __half* eaO1 = eaOutT + (size_t)(c2 + 2) * PADCAP;

    auto accum = [&](const __half* __restrict__ base, uint4 prtv, uint4 e0v, uint4 e1v) {
        unsigned pr0 = prtv.x & 0xFFFFu, pr1 = prtv.x >> 16;
        unsigned pr2 = prtv.y & 0xFFFFu, pr3 = prtv.y >> 16;
        unsigned pr4 = prtv.z & 0xFFFFu, pr5 = prtv.z >> 16;
        unsigned pr6 = prtv.w & 0xFFFFu, pr7 = prtv.w >> 16;
        __half g0h[8], g1h[8];
        const __half* r0p = base + (size_t)pr0 * 128u; g0h[0] = r0p[gOff0]; g1h[0] = r0p[gOff1];
        const __half* r1p = base + (size_t)pr1 * 128u; g0h[1] = r1p[gOff0]; g1h[1] = r1p[gOff1];
        const __half* r2p = base + (size_t)pr2 * 128u; g0h[2] = r2p[gOff0]; g1h[2] = r2p[gOff1];
        const __half* r3p = base + (size_t)pr3 * 128u; g0h[3] = r3p[gOff0]; g1h[3] = r3p[gOff1];
        const __half* r4p = base + (size_t)pr4 * 128u; g0h[4] = r4p[gOff0]; g1h[4] = r4p[gOff1];
        const __half* r5p = base + (size_t)pr5 * 128u; g0h[5] = r5p[gOff0]; g1h[5] = r5p[gOff1];
        const __half* r6p = base + (size_t)pr6 * 128u; g0h[6] = r6p[gOff0]; g1h[6] = r6p[gOff1];
        const __half* r7p = base + (size_t)pr7 * 128u; g0h[7] = r7p[gOff0]; g1h[7] = r7p[gOff1];
        union { uint4 u4; __half2 h2[4]; } E0, E1;
        E0.u4 = e0v; E1.u4 = e1v;
#pragma unroll
        for (int ii = 0; ii < 4; ++ii) {   // v_pack + v_dot2_f32_f16
            h0 = fdot2f(E0.h2[ii], __halves2half2(g0h[2 * ii], g0h[2 * ii + 1]), h0);
            h1 = fdot2f(E1.h2[ii], __halves2half2(g1h[2 * ii], g1h[2 * ii + 1]), h1);
        }
    };

    // pre-issue first OUT batch metadata (hides its latency under the in-loop)
    uint4 oprt = {0, 0, 0, 0}, oe0 = {0, 0, 0, 0}, oe1 = {0, 0, 0, 0};
    if (bo0 < boE) {
        oprt = *(const uint4*)(outPrt + bo0);
        oe0  = *(const uint4*)(eaO0 + bo0);
        oe1  = *(const uint4*)(eaO1 + bo0);
    }

    if (bi0 < biE) {
        uint4 cprt = *(const uint4*)(inPrt + bi0);
        uint4 ce0  = *(const uint4*)(eaI0 + bi0);
        uint4 ce1  = *(const uint4*)(eaI1 + bi0);
        for (int b = bi0; b < biE; b += 8) {
            uint4 nprt = cprt, ne0 = ce0, ne1 = ce1;
            if (b + 8 < biE) {                       // prefetch next batch meta
                nprt = *(const uint4*)(inPrt + b + 8);
                ne0  = *(const uint4*)(eaI0 + b + 8);
                ne1  = *(const uint4*)(eaI1 + b + 8);
            }
            accum(p, cprt, ce0, ce1);
            cprt = nprt; ce0 = ne0; ce1 = ne1;
        }
    }
    if (bo0 < boE) {
        uint4 cprt = oprt, ce0 = oe0, ce1 = oe1;     // already in flight
        for (int b = bo0; b < boE; b += 8) {
            uint4 nprt = cprt, ne0 = ce0, ne1 = ce1;
            if (b + 8 < boE) {
                nprt = *(const uint4*)(outPrt + b + 8);
                ne0  = *(const uint4*)(eaO0 + b + 8);
                ne1  = *(const uint4*)(eaO1 + b + 8);
            }
            accum(q, cprt, ce0, ce1);
            cprt = nprt; ce0 = ne0; ce1 = ne1;
        }
    }

    float t0 = fast_tanh(h0);   // class c2, dim k (lane-local)
    float t1 = fast_tanh(h1);   // class c2+2, dim k
    float hh0 = nb2[k], hh1 = hh0;
#pragma unroll
    for (int kk = 0; kk < 32; ++kk) {
        float w = nW2[kk * 32 + k];                  // L1-resident broadcast
        float s0 = __shfl(t0, (int)(c2 * 32 + kk), 64);   // t(class c2, kk)
        float s1 = __shfl(t1, (int)(c2 * 32 + kk), 64);   // t(class c2+2, kk)
        hh0 += s0 * w;
        hh1 += s1 * w;
    }
    m[((size_t)n * 4 + c2) * HI + k]     = __float2half_rn(fast_tanh(hh0));
    m[((size_t)n * 4 + c2 + 2) * HI + k] = __float2half_rn(fast_tanh(hh1));
}

extern "C" void kernel_launch(void* const* d_in, const int* in_sizes, int n_in,
                              void* d_out, int out_size, void* d_ws, size_t ws_size,
                              hipStream_t stream) {
    const float* x   = (const float*)d_in[0];
    const int*   ei  = (const int*)d_in[1];
    const float* inW = (const float*)d_in[2];
    const float* inb = (const float*)d_in[3];
    const float* eW1 = (const float*)d_in[4];
    const float* eb1 = (const float*)d_in[5];
    const float* eW2 = (const float*)d_in[6];
    const float* eb2 = (const float*)d_in[7];
    const float* nW1 = (const float*)d_in[8];
    const float* nb1 = (const float*)d_in[9];
    const float* nW2 = (const float*)d_in[10];
    const float* nb2 = (const float*)d_in[11];
    float* out = (float*)d_out;

    // Workspace: m 14.4 | u..rbuf 64 | ea 10.75 | CSR blocks (10.09 MB each).
    // Merged mode (all 3 planes' CSR built upfront) needs 119.5 MB; falls back
    // to the per-plane rebuild (99.3 MB) if ws_size is insufficient.
    __half* m     = (__half*)d_ws;
    __half* u     = m + (size_t)ROWS_P * HI;
    __half* v     = u + (size_t)ROWS_P * 32;
    __half* p     = v + (size_t)ROWS_P * 32;
    __half* q     = p + (size_t)ROWS_P * 32;
    __half* rbuf  = q + (size_t)ROWS_P * 32;
    __half* eaIn  = rbuf + (size_t)ROWS_P * 32;
    __half* eaOut = eaIn + (size_t)PADCAP * 4;
    int*    csr   = (int*)(eaOut + (size_t)PADCAP * 4);   // 16B-aligned
    int*    tmpLi = (int*)u;   // 3x400k ints = 4.8 MB <= u's 12.8 MB; dead until gemm5

    const size_t csrBaseBytes = (size_t)((char*)csr - (char*)d_ws);
    const bool merged = ws_size >= csrBaseBytes + 3u * (size_t)CSR_STRIDE * 4 + 256;

    const size_t zeroEA  = (size_t)PADCAP * 4 * 2 * 2;        // eaIn|eaOut
    const size_t cntB    = (size_t)2 * N_NODES * 4;
    const size_t prtB    = (size_t)2 * PADCAP * 2;

    if (merged) {   // build all 3 planes' CSR upfront (one pass, 3x grids)
        for (int j = 0; j < 3; ++j) {
            int* bj = csr + (size_t)j * CSR_STRIDE;
            hipMemsetAsync(bj + OFF_CNT, 0, cntB, stream);
            hipMemsetAsync(bj + OFF_PRT, 0, prtB, stream);
        }
        k_pass1<<<3 * GRIDE, 256, 0, stream>>>(ei, csr, tmpLi);
        k_scanA<<<9 * NCHUNKS, 256, 0, stream>>>(csr);
        k_scanB<<<9, 256, 0, stream>>>(csr);
        k_scanC<<<9 * NCHUNKS, 256, 0, stream>>>(csr);
        k_pass2<<<3 * GRIDE * SLICES, 256, 0, stream>>>(ei, csr, tmpLi);
    }

    for (int j = 0; j < 3; ++j) {
        const float* eW1j = eW1 + j * 72 * 32;
        const float* eb1j = eb1 + j * 32;
        const float* eW2j = eW2 + j * 32;
        const float* eb2j = eb2 + j;
        const float* nW1j = nW1 + j * 108 * 32;
        const float* nb1j = nb1 + j * 32;
        const float* nW2j = nW2 + j * 1024;
        const float* nb2j = nb2 + j * 32;

        int* bj = csr + (merged ? (size_t)j * CSR_STRIDE : 0);
        if (!merged) {   // per-plane rebuild into block 0
            hipMemsetAsync(bj + OFF_CNT, 0, cntB, stream);
            hipMemsetAsync(bj + OFF_PRT, 0, prtB, stream);
            k_pass1<<<GRIDE, 256, 0, stream>>>(ei + (size_t)j * 2 * N_EDGES, bj, tmpLi);
            k_scanA<<<3 * NCHUNKS, 256, 0, stream>>>(bj);
            k_scanB<<<3, 256, 0, stream>>>(bj);
            k_scanC<<<3 * NCHUNKS, 256, 0, stream>>>(bj);
            k_pass2<<<GRIDE * SLICES, 256, 0, stream>>>(ei + (size_t)j * 2 * N_EDGES,
                                                        bj, tmpLi);
        }
        const int4* edgeRec = (const int4*)(bj + OFF_EREC);
        const int*  pinOff  = bj + OFF_OFFS + (N_NODES + 1);
        const int*  poutOff = bj + OFF_OFFS + 2 * (N_NODES + 1);
        const unsigned short* inPrt  = (const unsigned short*)(bj + OFF_PRT);
        const unsigned short* outPrt = inPrt + PADCAP;

        hipMemsetAsync(eaIn, 0, zeroEA, stream);
        k_init<<<(N_NODES * HI + 255) / 256, 256, 0, stream>>>(
            x + (size_t)j * N_NODES * 4, inW + j * 128, inb + j * 32, m);

        for (int it = 0; it < 3; ++it) {
            k_gemm5<<<ROWS_P / 32, 320, 0, stream>>>(m, eW1j, nW1j, eb1j, nb1j,
                                                     u, v, p, q, rbuf);
            k_edge<false><<<N_EDGES * 4 / 256, 256, 0, stream>>>(
                edgeRec, u, v, eW2j, eb2j, eaIn, eaOut, nullptr);
            k_node<<<N_NODES, 64, 0, stream>>>(m, rbuf, p, q, eaIn, eaOut,
                                               pinOff, poutOff, inPrt, outPrt,
                                               nW2j, nb2j);
        }
        k_gemm2<<<ROWS_P / 32, 256, 0, stream>>>(m, eW1j, eW1j + 36 * 32, eb1j, u, v);
        k_edge<true><<<N_EDGES * 4 / 256, 256, 0, stream>>>(
            edgeRec, u, v, eW2j, eb2j, nullptr, nullptr,
            out + (size_t)j * N_EDGES * 4);
    }
}